// Round 4
// baseline (71.305 us; speedup 1.0000x reference)
//
#include <hip/hip_runtime.h>

#define IN_F  8192
#define OUT_F 8192
#define BATCH 16
#define KSPLIT 8
#define KCHUNK (IN_F / KSPLIT)   // 1024 k per block
#define KSTEP  128
#define NSTEPS (KCHUNK / KSTEP)  // 8
#define ROWS_PER_BLOCK 16        // 4 waves x 4 rows
#define THREADS 256

typedef const __attribute__((address_space(1))) unsigned int g_u32;
typedef __attribute__((address_space(3))) unsigned int s_u32;

// out[b][o] = bias[o]  (re-inits the atomic accumulator every call)
__global__ __launch_bounds__(256)
void init_out_kernel(const float* __restrict__ bias, float* __restrict__ out)
{
    const int i = blockIdx.x * 256 + threadIdx.x;
    out[i] = bias[i & (OUT_F - 1)];
}

__global__ __launch_bounds__(THREADS, 4)
void gptq_main_kernel(const float* __restrict__ x,
                      const int*  __restrict__ qw,
                      const float* __restrict__ scale,
                      float* __restrict__ out)
{
    __shared__ __align__(16) float xs[2][BATCH * KSTEP];   // 2 x 8 KB

    const int tid  = threadIdx.x;
    const int lane = tid & 63;
    const int wave = tid >> 6;
    const int row0 = blockIdx.x * ROWS_PER_BLOCK + wave * 4;
    const int kbase = blockIdx.y * KCHUNK;

    // x staging: wave w stages rows [4w,4w+4) in 2 gloads of 1KB.
    // gload j covers rows 4w+2j (lanes 0-31) and 4w+2j+1 (lanes 32-63):
    // per-lane SRC handles the IN_F row stride; LDS dest stays linear.
    const int   xrow = wave * 4 + (lane >> 5);
    const float* xsrc = x + (size_t)xrow * IN_F + kbase + (lane & 31) * 4;
    const int*   qsrc = qw + (size_t)row0 * IN_F + kbase + lane * 2;

    // ---- prologue: stage x tile 0 (2 gloads), prefetch w tile 0 (4 dwordx2) ----
    #pragma unroll
    for (int j = 0; j < 2; ++j)
        __builtin_amdgcn_global_load_lds((g_u32*)(xsrc + (size_t)(2 * j) * IN_F),
                                         (s_u32*)&xs[0][(wave * 4 + 2 * j) * KSTEP],
                                         16, 0, 0);
    __builtin_amdgcn_sched_barrier(0);   // keep x-gloads oldest in the vmcnt queue

    int2 wcur[4];
    #pragma unroll
    for (int r = 0; r < 4; ++r)
        wcur[r] = *reinterpret_cast<const int2*>(qsrc + (size_t)r * IN_F);
    __builtin_amdgcn_sched_barrier(0);

    float acc[64];
    #pragma unroll
    for (int i = 0; i < 64; ++i) acc[i] = 0.0f;

    // drain the 2 x-gloads (+ any stray prologue load); weights stay in flight
    asm volatile("s_waitcnt vmcnt(4)" ::: "memory");
    __builtin_amdgcn_sched_barrier(0);
    __builtin_amdgcn_s_barrier();
    __builtin_amdgcn_sched_barrier(0);

    #pragma unroll
    for (int step = 0; step < NSTEPS; ++step) {
        const int buf = step & 1;
        const bool has_next = (step + 1 < NSTEPS);
        const int kg = (step + 1) * KSTEP;

        // issue next x tile first (must stay the oldest outstanding loads)
        if (has_next) {
            #pragma unroll
            for (int j = 0; j < 2; ++j)
                __builtin_amdgcn_global_load_lds((g_u32*)(xsrc + kg + (size_t)(2 * j) * IN_F),
                                                 (s_u32*)&xs[buf ^ 1][(wave * 4 + 2 * j) * KSTEP],
                                                 16, 0, 0);
        }
        __builtin_amdgcn_sched_barrier(0);

        // next weights -> registers; they float across the barrier below
        int2 wnext[4];
        if (has_next) {
            #pragma unroll
            for (int r = 0; r < 4; ++r)
                wnext[r] = *reinterpret_cast<const int2*>(qsrc + kg + (size_t)r * IN_F);
        }
        __builtin_amdgcn_sched_barrier(0);

        // int4-valued weights are exact in fp32 (compiler waits vmcnt for wcur here)
        float wf[4][2];
        #pragma unroll
        for (int r = 0; r < 4; ++r) {
            wf[r][0] = (float)wcur[r].x;
            wf[r][1] = (float)wcur[r].y;
        }

        // 16 ds_read_b64 + 128 v_fmac per thread per step
        #pragma unroll
        for (int b = 0; b < BATCH; ++b) {
            const float2 xv = *reinterpret_cast<const float2*>(&xs[buf][b * KSTEP + lane * 2]);
            #pragma unroll
            for (int r = 0; r < 4; ++r) {
                acc[r * 16 + b] += wf[r][0] * xv.x;
                acc[r * 16 + b] += wf[r][1] * xv.y;
            }
        }

        if (has_next) {
            // counted wait: queue is [g0,g1,w0..w3] -> drain only the 2 x-gloads
            asm volatile("s_waitcnt vmcnt(4)" ::: "memory");
            __builtin_amdgcn_sched_barrier(0);
            __builtin_amdgcn_s_barrier();
            __builtin_amdgcn_sched_barrier(0);
            #pragma unroll
            for (int r = 0; r < 4; ++r) wcur[r] = wnext[r];
        }
    }

    // ---- recursive-halving reduction across the 64-lane k-split ----
    #pragma unroll
    for (int m = 1, half = 32; m <= 32; m <<= 1, half >>= 1) {
        const bool hi = (lane & m) != 0;
        #pragma unroll
        for (int i = 0; i < half; ++i) {
            const float send = hi ? acc[i] : acc[half + i];
            const float recv = __shfl_xor(send, m, 64);
            const float keep = hi ? acc[half + i] : acc[i];
            acc[i] = keep + recv;
        }
    }

    const int idx = ((lane & 1)  << 5) | ((lane & 2)  << 3) | ((lane & 4)  << 1)
                  | ((lane & 8)  >> 1) | ((lane & 16) >> 3) | ((lane & 32) >> 5);
    const int r = idx >> 4;        // row within wave's 4
    const int b = idx & 15;        // batch
    const int o = row0 + r;

    atomicAdd(out + (size_t)b * OUT_F + o, acc[0] * scale[0]);
}

extern "C" void kernel_launch(void* const* d_in, const int* in_sizes, int n_in,
                              void* d_out, int out_size, void* d_ws, size_t ws_size,
                              hipStream_t stream) {
    const float* x     = (const float*)d_in[0];
    const int*   qw    = (const int*)d_in[1];
    const float* scale = (const float*)d_in[2];
    const float* bias  = (const float*)d_in[3];
    float*       out   = (float*)d_out;

    init_out_kernel<<<(BATCH * OUT_F) / 256, 256, 0, stream>>>(bias, out);

    dim3 grid(OUT_F / ROWS_PER_BLOCK, KSPLIT);   // 512 x 8 = 4096 blocks
    gptq_main_kernel<<<grid, THREADS, 0, stream>>>(x, qw, scale, out);
}